// Round 1
// baseline (328.807 us; speedup 1.0000x reference)
//
#include <hip/hip_runtime.h>
#include <hip/hip_bf16.h>

typedef __bf16 bf16_t;
typedef __bf16 bf16x8 __attribute__((ext_vector_type(8)));
typedef float  f32x4  __attribute__((ext_vector_type(4)));
typedef _Float16 f16_t;

#define LDS_SWZ(r, c16) ((((c16)*16) ^ (((r)&7)*16)))

// ---------------------------------------------------------------- weight prep
struct WPack { const float* in[5]; bf16_t* out[5]; };

__global__ __launch_bounds__(256) void k_prep_w(WPack p)
{
    __shared__ float tile[32][33];
    const int wi = blockIdx.z;
    const float* in = p.in[wi];
    bf16_t* out = p.out[wi];
    const int k0 = blockIdx.x * 32, n0 = blockIdx.y * 32;
    for (int base = 0; base < 32 * 32; base += 256) {
        int idx = base + threadIdx.x; int r = idx >> 5, c = idx & 31;
        tile[r][c] = in[(k0 + r) * 768 + n0 + c];
    }
    __syncthreads();
    for (int base = 0; base < 32 * 32; base += 256) {
        int idx = base + threadIdx.x; int r = idx >> 5, c = idx & 31;
        out[(n0 + r) * 768 + k0 + c] = (bf16_t)tile[c][r];
    }
}

__global__ __launch_bounds__(256) void k_prep_wb(
    const float* __restrict__ Wb, const float* __restrict__ lnzw,
    const float* __restrict__ lnzb, float* __restrict__ WbW,
    float* __restrict__ WbS, float* __restrict__ WbC)
{
    const int t = threadIdx.x;
    for (int idx = t; idx < 2048; idx += 256) {
        int d = idx >> 4;
        WbW[idx] = lnzw[d] * Wb[idx];
    }
    if (t < 16) {
        float s = 0.f, c = 0.f;
        for (int d = 0; d < 128; d++) {
            float wb = Wb[d * 16 + t];
            s += lnzw[d] * wb;
            c += lnzb[d] * wb;
        }
        WbS[t] = s; WbC[t] = c;
    }
}

// ---------------------------------------------------------------- LayerNorm(a)
__global__ __launch_bounds__(256) void k_ln_a(
    const float* __restrict__ a, const float* __restrict__ w,
    const float* __restrict__ b, bf16_t* __restrict__ an)
{
    const int row = blockIdx.x, t = threadIdx.x;
    const float* x = a + row * 768;
    float v0 = x[t], v1 = x[t + 256], v2 = x[t + 512];
    float s = v0 + v1 + v2;
    float s2 = v0 * v0 + v1 * v1 + v2 * v2;
#pragma unroll
    for (int o = 32; o; o >>= 1) { s += __shfl_xor(s, o); s2 += __shfl_xor(s2, o); }
    __shared__ float red[8];
    if ((t & 63) == 0) { red[t >> 6] = s; red[4 + (t >> 6)] = s2; }
    __syncthreads();
    float S  = red[0] + red[1] + red[2] + red[3];
    float S2 = red[4] + red[5] + red[6] + red[7];
    float mean = S * (1.f / 768.f);
    float var  = S2 * (1.f / 768.f) - mean * mean;
    float rinv = rsqrtf(var + 1e-5f);
    bf16_t* op = an + row * 768;
    op[t]       = (bf16_t)(((v0 - mean) * rinv) * w[t]       + b[t]);
    op[t + 256] = (bf16_t)(((v1 - mean) * rinv) * w[t + 256] + b[t + 256]);
    op[t + 512] = (bf16_t)(((v2 - mean) * rinv) * w[t + 512] + b[t + 512]);
}

// --------------------------------------------- generic 1024x768x768 MFMA GEMM
// C = A[1024x768]_bf16 @ W, with BT = W^T (row n contiguous in k), both bf16.
// mode 0: q  -> bf16, (acc+bias[col])*1/sqrt(48)
// mode 1: k  -> bf16
// mode 2: vT -> bf16 scattered transposed out[col*1024+row]
// mode 3: g  -> f32 sigmoid
// mode 4: out-> f32
__global__ __launch_bounds__(256) void k_gemm768(
    const bf16_t* __restrict__ A, const bf16_t* __restrict__ BT,
    void* __restrict__ out, const float* __restrict__ bias, int mode)
{
    __shared__ bf16_t lA[128 * 64];
    __shared__ bf16_t lB[128 * 64];
    const int t = threadIdx.x;
    const int i0 = blockIdx.x * 128, n0 = blockIdx.y * 128;
    const int w = t >> 6, l = t & 63;
    const int wm = (w >> 1) * 64, wn = (w & 1) * 64;
    const int lm = l & 15, lg = l >> 4;
    f32x4 acc[4][4] = {};
    for (int k0 = 0; k0 < 768; k0 += 64) {
        __syncthreads();
#pragma unroll
        for (int cc = 0; cc < 4; cc++) {
            int ch = t + 256 * cc; int r = ch >> 3, c16 = ch & 7;
            bf16x8 va = *(const bf16x8*)(A  + (i0 + r) * 768 + k0 + c16 * 8);
            bf16x8 vb = *(const bf16x8*)(BT + (n0 + r) * 768 + k0 + c16 * 8);
            *(bf16x8*)((char*)lA + r * 128 + LDS_SWZ(r, c16)) = va;
            *(bf16x8*)((char*)lB + r * 128 + LDS_SWZ(r, c16)) = vb;
        }
        __syncthreads();
#pragma unroll
        for (int kk = 0; kk < 2; kk++) {
            bf16x8 af[4], bfr[4];
#pragma unroll
            for (int m = 0; m < 4; m++) {
                int r = wm + m * 16 + lm;
                af[m] = *(const bf16x8*)((char*)lA + r * 128 + LDS_SWZ(r, kk * 4 + lg));
            }
#pragma unroll
            for (int n = 0; n < 4; n++) {
                int r = wn + n * 16 + lm;
                bfr[n] = *(const bf16x8*)((char*)lB + r * 128 + LDS_SWZ(r, kk * 4 + lg));
            }
#pragma unroll
            for (int m = 0; m < 4; m++)
#pragma unroll
                for (int n = 0; n < 4; n++)
                    acc[m][n] = __builtin_amdgcn_mfma_f32_16x16x32_bf16(af[m], bfr[n], acc[m][n], 0, 0, 0);
        }
    }
#pragma unroll
    for (int m = 0; m < 4; m++)
#pragma unroll
        for (int n = 0; n < 4; n++) {
            const int col = n0 + wn + n * 16 + lm;
#pragma unroll
            for (int r = 0; r < 4; r++) {
                const int row = i0 + wm + m * 16 + lg * 4 + r;
                float v = acc[m][n][r];
                if (mode == 0) {
                    ((bf16_t*)out)[row * 768 + col] = (bf16_t)((v + bias[col]) * 0.14433756729740643f);
                } else if (mode == 1) {
                    ((bf16_t*)out)[row * 768 + col] = (bf16_t)v;
                } else if (mode == 2) {
                    ((bf16_t*)out)[col * 1024 + row] = (bf16_t)v;
                } else if (mode == 3) {
                    ((float*)out)[row * 768 + col] = 1.f / (1.f + __expf(-v));
                } else {
                    ((float*)out)[row * 768 + col] = v;
                }
            }
        }
}

// ------------------------------------------------- qk[h][i][j] batched MFMA
__global__ __launch_bounds__(256) void k_qk(
    const bf16_t* __restrict__ q, const bf16_t* __restrict__ k, bf16_t* __restrict__ qk)
{
    __shared__ bf16_t lA[128 * 64];
    __shared__ bf16_t lB[128 * 64];
    const int t = threadIdx.x;
    const int i0 = blockIdx.x * 128, j0 = blockIdx.y * 128, h = blockIdx.z;
    const int w = t >> 6, l = t & 63;
    const int wm = (w >> 1) * 64, wn = (w & 1) * 64;
    const int lm = l & 15, lg = l >> 4;
#pragma unroll
    for (int cc = 0; cc < 4; cc++) {
        int ch = t + 256 * cc; int r = ch >> 3, c16 = ch & 7;
        bf16x8 va, vb;
        if (c16 < 6) {
            va = *(const bf16x8*)(q + (i0 + r) * 768 + h * 48 + c16 * 8);
            vb = *(const bf16x8*)(k + (j0 + r) * 768 + h * 48 + c16 * 8);
        } else {
#pragma unroll
            for (int e = 0; e < 8; e++) { va[e] = (bf16_t)0.f; vb[e] = (bf16_t)0.f; }
        }
        *(bf16x8*)((char*)lA + r * 128 + LDS_SWZ(r, c16)) = va;
        *(bf16x8*)((char*)lB + r * 128 + LDS_SWZ(r, c16)) = vb;
    }
    __syncthreads();
    f32x4 acc[4][4] = {};
#pragma unroll
    for (int kk = 0; kk < 2; kk++) {
        bf16x8 af[4], bfr[4];
#pragma unroll
        for (int m = 0; m < 4; m++) {
            int r = wm + m * 16 + lm;
            af[m] = *(const bf16x8*)((char*)lA + r * 128 + LDS_SWZ(r, kk * 4 + lg));
        }
#pragma unroll
        for (int n = 0; n < 4; n++) {
            int r = wn + n * 16 + lm;
            bfr[n] = *(const bf16x8*)((char*)lB + r * 128 + LDS_SWZ(r, kk * 4 + lg));
        }
#pragma unroll
        for (int m = 0; m < 4; m++)
#pragma unroll
            for (int n = 0; n < 4; n++)
                acc[m][n] = __builtin_amdgcn_mfma_f32_16x16x32_bf16(af[m], bfr[n], acc[m][n], 0, 0, 0);
    }
    bf16_t* orow = qk + ((long)h << 20);
#pragma unroll
    for (int m = 0; m < 4; m++)
#pragma unroll
        for (int n = 0; n < 4; n++) {
            const int col = j0 + wn + n * 16 + lm;
#pragma unroll
            for (int r = 0; r < 4; r++) {
                const int row = i0 + wm + m * 16 + lg * 4 + r;
                orow[(long)row * 1024 + col] = (bf16_t)acc[m][n][r];
            }
        }
}

// ------------------------- fused: stream z, LN+bpair, + qk, softmax -> att
// one block per row i; att overwrites qk in place.
__global__ __launch_bounds__(256) void k_scores(
    const float* __restrict__ z, bf16_t* qkatt,
    const float* __restrict__ WbW, const float* __restrict__ WbS,
    const float* __restrict__ WbC, const float* __restrict__ mask)
{
    __shared__ f16_t  s_lds[16 * 1032];
    __shared__ bf16_t z_lds[64 * 136];
    __shared__ float  wbw[128 * 16];
    const int t = threadIdx.x;
    const long i = blockIdx.x;
    const int jq = t >> 2, hg = t & 3;

    float r_wbs[4], r_wbc[4];
#pragma unroll
    for (int hh = 0; hh < 4; hh++) { r_wbs[hh] = WbS[hg * 4 + hh]; r_wbc[hh] = WbC[hg * 4 + hh]; }

    const float* zrow = z + i * (1024 * 128);
    f32x4 buf0[8], buf1[8];

    auto issue = [&](f32x4 (&buf)[8], int jt) {
        const float* base = zrow + jt * (64 * 128);
#pragma unroll
        for (int p = 0; p < 4; p++) {
            int ch = t * 2 + 512 * p;
            int j = ch >> 5, q4 = ch & 31;
            buf[2 * p]     = *(const f32x4*)(base + j * 128 + q4 * 4);
            buf[2 * p + 1] = *(const f32x4*)(base + j * 128 + q4 * 4 + 4);
        }
    };
    auto stash = [&](f32x4 (&buf)[8]) {
#pragma unroll
        for (int p = 0; p < 4; p++) {
            int ch = t * 2 + 512 * p;
            int j = ch >> 5, q4 = ch & 31;
            bf16x8 v;
#pragma unroll
            for (int e = 0; e < 4; e++) {
                v[e]     = (bf16_t)buf[2 * p][e];
                v[4 + e] = (bf16_t)buf[2 * p + 1][e];
            }
            *(bf16x8*)((char*)z_lds + j * 272 + q4 * 8) = v;
        }
    };
    auto compute = [&](int jt) {
        const int jg = jt * 64 + jq;
        float sm = 0.f, sq = 0.f;
#pragma unroll
        for (int c = 0; c < 4; c++) {
            bf16x8 zc = *(const bf16x8*)((const char*)z_lds + jq * 272 + hg * 64 + c * 16);
#pragma unroll
            for (int e = 0; e < 8; e++) { float x = (float)zc[e]; sm += x; sq += x * x; }
        }
        sm += __shfl_xor(sm, 1); sm += __shfl_xor(sm, 2);
        sq += __shfl_xor(sq, 1); sq += __shfl_xor(sq, 2);
        const float mean = sm * (1.f / 128.f);
        const float var  = sq * (1.f / 128.f) - mean * mean;
        const float rinv = rsqrtf(var + 1e-5f);
        float d[4] = {0.f, 0.f, 0.f, 0.f};
#pragma unroll
        for (int c = 0; c < 16; c++) {
            bf16x8 zc = *(const bf16x8*)((const char*)z_lds + jq * 272 + c * 16);
#pragma unroll
            for (int e = 0; e < 8; e++) {
                float x = (float)zc[e];
                f32x4 wv = *(const f32x4*)(wbw + (c * 8 + e) * 16 + hg * 4);
#pragma unroll
                for (int u = 0; u < 4; u++) d[u] += x * wv[u];
            }
        }
#pragma unroll
        for (int hh = 0; hh < 4; hh++) {
            float bp = rinv * (d[hh] - mean * r_wbs[hh]) + r_wbc[hh];
            int h = hg * 4 + hh;
            float sv = (float)s_lds[h * 1032 + jg] + bp;
            s_lds[h * 1032 + jg] = (f16_t)sv;
        }
    };

    issue(buf0, 0);

    for (int idx = t; idx < 2048; idx += 256) wbw[idx] = WbW[idx];
    const bf16_t* qkrow = qkatt + i * 1024;
    for (int c = t; c < 2048; c += 256) {
        int h = c >> 7, j0 = (c & 127) * 8;
        bf16x8 v = *(const bf16x8*)(qkrow + ((long)h << 20) + j0);
        f32x4 ma = *(const f32x4*)(mask + j0);
        f32x4 mb = *(const f32x4*)(mask + j0 + 4);
#pragma unroll
        for (int e = 0; e < 4; e++) {
            s_lds[h * 1032 + j0 + e]     = (f16_t)((float)v[e]     - 60000.f * (1.f - ma[e]));
            s_lds[h * 1032 + j0 + 4 + e] = (f16_t)((float)v[4 + e] - 60000.f * (1.f - mb[e]));
        }
    }

#pragma unroll 1
    for (int jt2 = 0; jt2 < 8; jt2++) {
        int jt = jt2 * 2;
        issue(buf1, jt + 1);
        __syncthreads();
        stash(buf0);
        __syncthreads();
        compute(jt);
        if (jt + 2 < 16) issue(buf0, jt + 2);
        __syncthreads();
        stash(buf1);
        __syncthreads();
        compute(jt + 1);
    }
    __syncthreads();

    const int wv = t >> 6, lane = t & 63;
#pragma unroll 1
    for (int hh = 0; hh < 4; hh++) {
        int h = wv * 4 + hh;
        float vals[16];
        float mx = -3.0e38f;
#pragma unroll
        for (int c = 0; c < 16; c++) {
            float v = (float)s_lds[h * 1032 + lane + c * 64];
            vals[c] = v; mx = fmaxf(mx, v);
        }
#pragma unroll
        for (int o = 32; o; o >>= 1) mx = fmaxf(mx, __shfl_xor(mx, o));
        float sum = 0.f;
#pragma unroll
        for (int c = 0; c < 16; c++) { float e = __expf(vals[c] - mx); vals[c] = e; sum += e; }
#pragma unroll
        for (int o = 32; o; o >>= 1) sum += __shfl_xor(sum, o);
        float r = 1.f / sum;
        bf16_t* arow = qkatt + ((long)h << 20) + i * 1024;
#pragma unroll
        for (int c = 0; c < 16; c++) arow[lane + c * 64] = (bf16_t)(vals[c] * r);
    }
}

// ------------------------------------------- per-h PV GEMM with g* epilogue
__global__ __launch_bounds__(256) void k_pv(
    const bf16_t* __restrict__ att, const bf16_t* __restrict__ vT,
    const float* __restrict__ g, bf16_t* __restrict__ go)
{
    __shared__ bf16_t lA[128 * 64];
    __shared__ bf16_t lB[48 * 64];
    const int t = threadIdx.x;
    const int i0 = blockIdx.x * 128, h = blockIdx.y;
    const int w = t >> 6, l = t & 63, lm = l & 15, lg = l >> 4;
    const int wm = w * 32;
    const bf16_t* Ab = att + ((long)h << 20);
    const bf16_t* Bb = vT + h * 48 * 1024;
    f32x4 acc[2][3] = {};
    for (int k0 = 0; k0 < 1024; k0 += 64) {
        __syncthreads();
#pragma unroll
        for (int cc = 0; cc < 4; cc++) {
            int ch = t + 256 * cc; int r = ch >> 3, c16 = ch & 7;
            bf16x8 va = *(const bf16x8*)(Ab + (long)(i0 + r) * 1024 + k0 + c16 * 8);
            *(bf16x8*)((char*)lA + r * 128 + LDS_SWZ(r, c16)) = va;
        }
#pragma unroll
        for (int cc = 0; cc < 2; cc++) {
            int ch = t + 256 * cc;
            if (ch < 384) {
                int r = ch >> 3, c16 = ch & 7;
                bf16x8 vb = *(const bf16x8*)(Bb + r * 1024 + k0 + c16 * 8);
                *(bf16x8*)((char*)lB + r * 128 + LDS_SWZ(r, c16)) = vb;
            }
        }
        __syncthreads();
#pragma unroll
        for (int kk = 0; kk < 2; kk++) {
            bf16x8 af[2], bfr[3];
#pragma unroll
            for (int m = 0; m < 2; m++) {
                int r = wm + m * 16 + lm;
                af[m] = *(const bf16x8*)((char*)lA + r * 128 + LDS_SWZ(r, kk * 4 + lg));
            }
#pragma unroll
            for (int n = 0; n < 3; n++) {
                int r = n * 16 + lm;
                bfr[n] = *(const bf16x8*)((char*)lB + r * 128 + LDS_SWZ(r, kk * 4 + lg));
            }
#pragma unroll
            for (int m = 0; m < 2; m++)
#pragma unroll
                for (int n = 0; n < 3; n++)
                    acc[m][n] = __builtin_amdgcn_mfma_f32_16x16x32_bf16(af[m], bfr[n], acc[m][n], 0, 0, 0);
        }
    }
#pragma unroll
    for (int m = 0; m < 2; m++)
#pragma unroll
        for (int n = 0; n < 3; n++) {
            const int col = h * 48 + n * 16 + lm;
#pragma unroll
            for (int r = 0; r < 4; r++) {
                const int row = i0 + wm + m * 16 + lg * 4 + r;
                float gv = g[row * 768 + col];
                go[row * 768 + col] = (bf16_t)(gv * acc[m][n][r]);
            }
        }
}

// ---------------------------------------------------------------------- launch
extern "C" void kernel_launch(void* const* d_in, const int* in_sizes, int n_in,
                              void* d_out, int out_size, void* d_ws, size_t ws_size,
                              hipStream_t stream)
{
    (void)in_sizes; (void)n_in;
    const float* a    = (const float*)d_in[0];
    const float* z    = (const float*)d_in[1];
    const float* mask = (const float*)d_in[2];
    const float* lnaw = (const float*)d_in[3];
    const float* lnab = (const float*)d_in[4];
    const float* lnzw = (const float*)d_in[5];
    const float* lnzb = (const float*)d_in[6];
    const float* Wq   = (const float*)d_in[7];
    const float* bq   = (const float*)d_in[8];
    const float* Wk   = (const float*)d_in[9];
    const float* Wv   = (const float*)d_in[10];
    const float* Wb   = (const float*)d_in[11];
    const float* Wg   = (const float*)d_in[12];
    const float* Wout = (const float*)d_in[13];

    char* p = (char*)d_ws; size_t off = 0;
    auto carve = [&](size_t bytes) -> void* {
        void* r = p + off; off += (bytes + 255) & ~(size_t)255; return r;
    };
    bf16_t* WT[5];
    for (int i = 0; i < 5; i++) WT[i] = (bf16_t*)carve(768 * 768 * 2);
    bf16_t* an  = (bf16_t*)carve(1024 * 768 * 2);
    bf16_t* qb  = (bf16_t*)carve(1024 * 768 * 2);
    bf16_t* kb  = (bf16_t*)carve(1024 * 768 * 2);
    bf16_t* vT  = (bf16_t*)carve(768 * 1024 * 2);
    float*  gf  = (float*) carve(1024 * 768 * 4);
    bf16_t* gob = (bf16_t*)carve(1024 * 768 * 2);
    float* WbWp = (float*)carve(128 * 16 * 4);
    float* WbSp = (float*)carve(64);
    float* WbCp = (float*)carve(64);
    bf16_t* qkatt = (bf16_t*)carve((size_t)16 * 1024 * 1024 * 2);

    if (ws_size < off) {  // clean failure signal instead of OOB corruption
        hipMemsetAsync(d_out, 0, (size_t)out_size * 4, stream);
        return;
    }

    WPack pk;
    pk.in[0] = Wq; pk.in[1] = Wk; pk.in[2] = Wv; pk.in[3] = Wg; pk.in[4] = Wout;
    for (int i = 0; i < 5; i++) pk.out[i] = WT[i];

    hipLaunchKernelGGL(k_prep_w, dim3(24, 24, 5), dim3(256), 0, stream, pk);
    hipLaunchKernelGGL(k_prep_wb, dim3(1), dim3(256), 0, stream, Wb, lnzw, lnzb, WbWp, WbSp, WbCp);
    hipLaunchKernelGGL(k_ln_a, dim3(1024), dim3(256), 0, stream, a, lnaw, lnab, an);
    hipLaunchKernelGGL(k_gemm768, dim3(8, 6), dim3(256), 0, stream, an, WT[0], (void*)qb, bq, 0);
    hipLaunchKernelGGL(k_gemm768, dim3(8, 6), dim3(256), 0, stream, an, WT[1], (void*)kb, (const float*)nullptr, 1);
    hipLaunchKernelGGL(k_gemm768, dim3(8, 6), dim3(256), 0, stream, an, WT[2], (void*)vT, (const float*)nullptr, 2);
    hipLaunchKernelGGL(k_gemm768, dim3(8, 6), dim3(256), 0, stream, an, WT[3], (void*)gf, (const float*)nullptr, 3);
    hipLaunchKernelGGL(k_qk, dim3(8, 8, 16), dim3(256), 0, stream, qb, kb, qkatt);
    hipLaunchKernelGGL(k_scores, dim3(1024), dim3(256), 0, stream, z, qkatt, WbWp, WbSp, WbCp, mask);
    hipLaunchKernelGGL(k_pv, dim3(8, 16), dim3(256), 0, stream, qkatt, vT, gf, gob);
    hipLaunchKernelGGL(k_gemm768, dim3(8, 6), dim3(256), 0, stream, gob, WT[4], d_out, (const float*)nullptr, 4);
}

// Round 2
// 232.427 us; speedup vs baseline: 1.4147x; 1.4147x over previous
//
#include <hip/hip_runtime.h>
#include <hip/hip_bf16.h>

typedef __bf16 bf16_t;
typedef __bf16 bf16x8 __attribute__((ext_vector_type(8)));
typedef float  f32x4  __attribute__((ext_vector_type(4)));
typedef _Float16 f16_t;

#define LDS_SWZ(r, c16) ((((c16)*16) ^ (((r)&7)*16)))

// ---------------------------------------------------------------- weight prep
struct WPack { const float* in[5]; bf16_t* out[5]; };

__global__ __launch_bounds__(256) void k_prep_w(WPack p)
{
    __shared__ float tile[32][33];
    const int wi = blockIdx.z;
    const float* in = p.in[wi];
    bf16_t* out = p.out[wi];
    const int k0 = blockIdx.x * 32, n0 = blockIdx.y * 32;
    for (int base = 0; base < 32 * 32; base += 256) {
        int idx = base + threadIdx.x; int r = idx >> 5, c = idx & 31;
        tile[r][c] = in[(k0 + r) * 768 + n0 + c];
    }
    __syncthreads();
    for (int base = 0; base < 32 * 32; base += 256) {
        int idx = base + threadIdx.x; int r = idx >> 5, c = idx & 31;
        out[(n0 + r) * 768 + k0 + c] = (bf16_t)tile[c][r];
    }
}

// WbWT[h][d] = bf16(lnzw[d]*Wb[d][h]);  WbS/WbC fp32 folds
__global__ __launch_bounds__(256) void k_prep_wb(
    const float* __restrict__ Wb, const float* __restrict__ lnzw,
    const float* __restrict__ lnzb, bf16_t* __restrict__ WbWT,
    float* __restrict__ WbS, float* __restrict__ WbC)
{
    const int t = threadIdx.x;
    for (int idx = t; idx < 2048; idx += 256) {
        int h = idx >> 7, d = idx & 127;
        WbWT[h * 128 + d] = (bf16_t)(lnzw[d] * Wb[d * 16 + h]);
    }
    if (t < 16) {
        float s = 0.f, c = 0.f;
        for (int d = 0; d < 128; d++) {
            float wb = Wb[d * 16 + t];
            s += lnzw[d] * wb;
            c += lnzb[d] * wb;
        }
        WbS[t] = s; WbC[t] = c;
    }
}

// ---------------------------------------------------------------- LayerNorm(a)
__global__ __launch_bounds__(256) void k_ln_a(
    const float* __restrict__ a, const float* __restrict__ w,
    const float* __restrict__ b, bf16_t* __restrict__ an)
{
    const int row = blockIdx.x, t = threadIdx.x;
    const float* x = a + row * 768;
    float v0 = x[t], v1 = x[t + 256], v2 = x[t + 512];
    float s = v0 + v1 + v2;
    float s2 = v0 * v0 + v1 * v1 + v2 * v2;
#pragma unroll
    for (int o = 32; o; o >>= 1) { s += __shfl_xor(s, o); s2 += __shfl_xor(s2, o); }
    __shared__ float red[8];
    if ((t & 63) == 0) { red[t >> 6] = s; red[4 + (t >> 6)] = s2; }
    __syncthreads();
    float S  = red[0] + red[1] + red[2] + red[3];
    float S2 = red[4] + red[5] + red[6] + red[7];
    float mean = S * (1.f / 768.f);
    float var  = S2 * (1.f / 768.f) - mean * mean;
    float rinv = rsqrtf(var + 1e-5f);
    bf16_t* op = an + row * 768;
    op[t]       = (bf16_t)(((v0 - mean) * rinv) * w[t]       + b[t]);
    op[t + 256] = (bf16_t)(((v1 - mean) * rinv) * w[t + 256] + b[t + 256]);
    op[t + 512] = (bf16_t)(((v2 - mean) * rinv) * w[t + 512] + b[t + 512]);
}

// --------------------------------------------- generic 1024x768x768 MFMA GEMM
__device__ __forceinline__ void gemm768_body(
    const bf16_t* __restrict__ A, const bf16_t* __restrict__ BT,
    void* __restrict__ out, const float* __restrict__ bias, int mode,
    int bx, int by)
{
    __shared__ bf16_t lA[128 * 64];
    __shared__ bf16_t lB[128 * 64];
    const int t = threadIdx.x;
    const int i0 = bx * 128, n0 = by * 128;
    const int w = t >> 6, l = t & 63;
    const int wm = (w >> 1) * 64, wn = (w & 1) * 64;
    const int lm = l & 15, lg = l >> 4;
    f32x4 acc[4][4] = {};
    for (int k0 = 0; k0 < 768; k0 += 64) {
        __syncthreads();
#pragma unroll
        for (int cc = 0; cc < 4; cc++) {
            int ch = t + 256 * cc; int r = ch >> 3, c16 = ch & 7;
            bf16x8 va = *(const bf16x8*)(A  + (i0 + r) * 768 + k0 + c16 * 8);
            bf16x8 vb = *(const bf16x8*)(BT + (n0 + r) * 768 + k0 + c16 * 8);
            *(bf16x8*)((char*)lA + r * 128 + LDS_SWZ(r, c16)) = va;
            *(bf16x8*)((char*)lB + r * 128 + LDS_SWZ(r, c16)) = vb;
        }
        __syncthreads();
#pragma unroll
        for (int kk = 0; kk < 2; kk++) {
            bf16x8 af[4], bfr[4];
#pragma unroll
            for (int m = 0; m < 4; m++) {
                int r = wm + m * 16 + lm;
                af[m] = *(const bf16x8*)((char*)lA + r * 128 + LDS_SWZ(r, kk * 4 + lg));
            }
#pragma unroll
            for (int n = 0; n < 4; n++) {
                int r = wn + n * 16 + lm;
                bfr[n] = *(const bf16x8*)((char*)lB + r * 128 + LDS_SWZ(r, kk * 4 + lg));
            }
#pragma unroll
            for (int m = 0; m < 4; m++)
#pragma unroll
                for (int n = 0; n < 4; n++)
                    acc[m][n] = __builtin_amdgcn_mfma_f32_16x16x32_bf16(af[m], bfr[n], acc[m][n], 0, 0, 0);
        }
    }
#pragma unroll
    for (int m = 0; m < 4; m++)
#pragma unroll
        for (int n = 0; n < 4; n++) {
            const int col = n0 + wn + n * 16 + lm;
#pragma unroll
            for (int r = 0; r < 4; r++) {
                const int row = i0 + wm + m * 16 + lg * 4 + r;
                float v = acc[m][n][r];
                if (mode == 0) {
                    ((bf16_t*)out)[row * 768 + col] = (bf16_t)((v + bias[col]) * 0.14433756729740643f);
                } else if (mode == 1) {
                    ((bf16_t*)out)[row * 768 + col] = (bf16_t)v;
                } else if (mode == 2) {
                    ((bf16_t*)out)[col * 1024 + row] = (bf16_t)v;
                } else if (mode == 3) {
                    ((float*)out)[row * 768 + col] = 1.f / (1.f + __expf(-v));
                } else {
                    ((float*)out)[row * 768 + col] = v;
                }
            }
        }
}

struct ProjPack { const bf16_t* A; const bf16_t* BT[4]; void* out[4]; const float* bias; };

// q,k,vT,g in one launch (z selects)
__global__ __launch_bounds__(256) void k_proj(ProjPack p)
{
    const int m = blockIdx.z;
    gemm768_body(p.A, p.BT[m], p.out[m], p.bias, m, blockIdx.x, blockIdx.y);
}

__global__ __launch_bounds__(256) void k_gemm768(
    const bf16_t* __restrict__ A, const bf16_t* __restrict__ BT,
    void* __restrict__ out, const float* __restrict__ bias, int mode)
{
    gemm768_body(A, BT, out, bias, mode, blockIdx.x, blockIdx.y);
}

// ------------------------------------------------- qk[h][i][j] batched MFMA
__global__ __launch_bounds__(256) void k_qk(
    const bf16_t* __restrict__ q, const bf16_t* __restrict__ k, bf16_t* __restrict__ qk)
{
    __shared__ bf16_t lA[128 * 64];
    __shared__ bf16_t lB[128 * 64];
    const int t = threadIdx.x;
    const int i0 = blockIdx.x * 128, j0 = blockIdx.y * 128, h = blockIdx.z;
    const int w = t >> 6, l = t & 63;
    const int wm = (w >> 1) * 64, wn = (w & 1) * 64;
    const int lm = l & 15, lg = l >> 4;
#pragma unroll
    for (int cc = 0; cc < 4; cc++) {
        int ch = t + 256 * cc; int r = ch >> 3, c16 = ch & 7;
        bf16x8 va, vb;
        if (c16 < 6) {
            va = *(const bf16x8*)(q + (i0 + r) * 768 + h * 48 + c16 * 8);
            vb = *(const bf16x8*)(k + (j0 + r) * 768 + h * 48 + c16 * 8);
        } else {
#pragma unroll
            for (int e = 0; e < 8; e++) { va[e] = (bf16_t)0.f; vb[e] = (bf16_t)0.f; }
        }
        *(bf16x8*)((char*)lA + r * 128 + LDS_SWZ(r, c16)) = va;
        *(bf16x8*)((char*)lB + r * 128 + LDS_SWZ(r, c16)) = vb;
    }
    __syncthreads();
    f32x4 acc[4][4] = {};
#pragma unroll
    for (int kk = 0; kk < 2; kk++) {
        bf16x8 af[4], bfr[4];
#pragma unroll
        for (int m = 0; m < 4; m++) {
            int r = wm + m * 16 + lm;
            af[m] = *(const bf16x8*)((char*)lA + r * 128 + LDS_SWZ(r, kk * 4 + lg));
        }
#pragma unroll
        for (int n = 0; n < 4; n++) {
            int r = wn + n * 16 + lm;
            bfr[n] = *(const bf16x8*)((char*)lB + r * 128 + LDS_SWZ(r, kk * 4 + lg));
        }
#pragma unroll
        for (int m = 0; m < 4; m++)
#pragma unroll
            for (int n = 0; n < 4; n++)
                acc[m][n] = __builtin_amdgcn_mfma_f32_16x16x32_bf16(af[m], bfr[n], acc[m][n], 0, 0, 0);
    }
    bf16_t* orow = qk + ((long)h << 20);
#pragma unroll
    for (int m = 0; m < 4; m++)
#pragma unroll
        for (int n = 0; n < 4; n++) {
            const int col = j0 + wn + n * 16 + lm;
#pragma unroll
            for (int r = 0; r < 4; r++) {
                const int row = i0 + wm + m * 16 + lg * 4 + r;
                orow[(long)row * 1024 + col] = (bf16_t)acc[m][n][r];
            }
        }
}

// ------------------------- fused: stream z, LN+bpair(MFMA), + qk, softmax -> att
// one block per row i; att overwrites qk in place.
// z tile LDS layout: row j (256B), two 128B halves, LDS_SWZ within half.
__global__ __launch_bounds__(256) void k_scores(
    const float* __restrict__ z, bf16_t* qkatt,
    const bf16_t* __restrict__ WbWT, const float* __restrict__ WbS,
    const float* __restrict__ WbC, const float* __restrict__ mask)
{
    __shared__ f16_t  s_lds[16 * 1032];      // 33024 B
    __shared__ bf16_t z_lds[64 * 128];       // 16384 B
    __shared__ bf16_t wbw_lds[16 * 128];     //  4096 B
    __shared__ float  stats_mean[64];
    __shared__ float  stats_rinv[64];
    const int t = threadIdx.x;
    const long i = blockIdx.x;
    const int w = t >> 6, l = t & 63;
    const int lm = l & 15, lg = l >> 4;

    const float* zrow = z + i * (1024 * 128);
    f32x4 buf0[8], buf1[8];

    auto issue = [&](f32x4 (&buf)[8], int jt) {
        const float* base = zrow + jt * (64 * 128);
#pragma unroll
        for (int p = 0; p < 4; p++) {
            int ch = t * 2 + 512 * p;
            int j = ch >> 5, q4 = ch & 31;
            buf[2 * p]     = *(const f32x4*)(base + j * 128 + q4 * 4);
            buf[2 * p + 1] = *(const f32x4*)(base + j * 128 + q4 * 4 + 4);
        }
    };
    // convert->LDS (MFMA layout) + per-row stats from fp32
    auto stash = [&](f32x4 (&buf)[8]) {
#pragma unroll
        for (int p = 0; p < 4; p++) {
            int j = (t >> 4) + 16 * p;         // row
            int d16 = t & 15;                  // 8-elem chunk index within row
            bf16x8 v;
            float s = 0.f, s2 = 0.f;
#pragma unroll
            for (int e = 0; e < 4; e++) {
                float x0 = buf[2 * p][e], x1 = buf[2 * p + 1][e];
                v[e]     = (bf16_t)x0;
                v[4 + e] = (bf16_t)x1;
                s += x0 + x1; s2 += x0 * x0 + x1 * x1;
            }
            *(bf16x8*)((char*)z_lds + j * 256 + ((d16 >> 3) << 7) + LDS_SWZ(j, d16 & 7)) = v;
#pragma unroll
            for (int o = 1; o < 16; o <<= 1) { s += __shfl_xor(s, o); s2 += __shfl_xor(s2, o); }
            if (d16 == 0) {
                float mean = s * (1.f / 128.f);
                float var  = s2 * (1.f / 128.f) - mean * mean;
                stats_mean[j] = mean;
                stats_rinv[j] = rsqrtf(var + 1e-5f);
            }
        }
    };

    issue(buf0, 0);

    // WbWT -> LDS (B-tile layout, rows h, 256B, swizzled halves)
    {
        int r = t >> 4, cidx = t & 15;
        bf16x8 v = *(const bf16x8*)(WbWT + r * 128 + cidx * 8);
        *(bf16x8*)((char*)wbw_lds + r * 256 + ((cidx >> 3) << 7) + LDS_SWZ(r, cidx & 7)) = v;
    }
    // init scores from qk + mask
    const bf16_t* qkrow = qkatt + i * 1024;
    for (int c = t; c < 2048; c += 256) {
        int h = c >> 7, j0 = (c & 127) * 8;
        bf16x8 v = *(const bf16x8*)(qkrow + ((long)h << 20) + j0);
        f32x4 ma = *(const f32x4*)(mask + j0);
        f32x4 mb = *(const f32x4*)(mask + j0 + 4);
#pragma unroll
        for (int e = 0; e < 4; e++) {
            s_lds[h * 1032 + j0 + e]     = (f16_t)((float)v[e]     - 60000.f * (1.f - ma[e]));
            s_lds[h * 1032 + j0 + 4 + e] = (f16_t)((float)v[4 + e] - 60000.f * (1.f - mb[e]));
        }
    }
    __syncthreads();

    // hoist B fragments (loop-invariant) + per-h folds
    bf16x8 bfrag[4];
#pragma unroll
    for (int s = 0; s < 4; s++)
        bfrag[s] = *(const bf16x8*)((char*)wbw_lds + lm * 256 + ((s >> 1) << 7)
                                    + LDS_SWZ(lm, ((s & 1) << 2) + lg));
    const float wbs = WbS[lm], wbc = WbC[lm];

    auto compute = [&](int jt) {
        f32x4 acc = {};
        const int jrow = w * 16 + lm;
#pragma unroll
        for (int s = 0; s < 4; s++) {
            bf16x8 af = *(const bf16x8*)((char*)z_lds + jrow * 256 + ((s >> 1) << 7)
                                         + LDS_SWZ(jrow, ((s & 1) << 2) + lg));
            acc = __builtin_amdgcn_mfma_f32_16x16x32_bf16(af, bfrag[s], acc, 0, 0, 0);
        }
#pragma unroll
        for (int r = 0; r < 4; r++) {
            int jl = w * 16 + lg * 4 + r;
            int jg = jt * 64 + jl;
            float bp = stats_rinv[jl] * (acc[r] - stats_mean[jl] * wbs) + wbc;
            int si = lm * 1032 + jg;
            s_lds[si] = (f16_t)((float)s_lds[si] + bp);
        }
    };

#pragma unroll 1
    for (int jt2 = 0; jt2 < 8; jt2++) {
        int jt = jt2 * 2;
        issue(buf1, jt + 1);
        __syncthreads();
        stash(buf0);
        __syncthreads();
        compute(jt);
        if (jt + 2 < 16) issue(buf0, jt + 2);
        __syncthreads();
        stash(buf1);
        __syncthreads();
        compute(jt + 1);
    }
    __syncthreads();

    // softmax over j per h; write att (in place over qk)
    const int lane = t & 63;
#pragma unroll 1
    for (int hh = 0; hh < 4; hh++) {
        int h = w * 4 + hh;
        float vals[16];
        float mx = -3.0e38f;
#pragma unroll
        for (int c = 0; c < 16; c++) {
            float v = (float)s_lds[h * 1032 + lane + c * 64];
            vals[c] = v; mx = fmaxf(mx, v);
        }
#pragma unroll
        for (int o = 32; o; o >>= 1) mx = fmaxf(mx, __shfl_xor(mx, o));
        float sum = 0.f;
#pragma unroll
        for (int c = 0; c < 16; c++) { float e = __expf(vals[c] - mx); vals[c] = e; sum += e; }
#pragma unroll
        for (int o = 32; o; o >>= 1) sum += __shfl_xor(sum, o);
        float r = 1.f / sum;
        bf16_t* arow = qkatt + ((long)h << 20) + i * 1024;
#pragma unroll
        for (int c = 0; c < 16; c++) arow[lane + c * 64] = (bf16_t)(vals[c] * r);
    }
}

// ------------------------------------------- per-h PV GEMM with g* epilogue
__global__ __launch_bounds__(256) void k_pv(
    const bf16_t* __restrict__ att, const bf16_t* __restrict__ vT,
    const float* __restrict__ g, bf16_t* __restrict__ go)
{
    __shared__ bf16_t lA[128 * 64];
    __shared__ bf16_t lB[48 * 64];
    const int t = threadIdx.x;
    const int i0 = blockIdx.x * 128, h = blockIdx.y;
    const int w = t >> 6, l = t & 63, lm = l & 15, lg = l >> 4;
    const int wm = w * 32;
    const bf16_t* Ab = att + ((long)h << 20);
    const bf16_t* Bb = vT + h * 48 * 1024;
    f32x4 acc[2][3] = {};
    for (int k0 = 0; k0 < 1024; k0 += 64) {
        __syncthreads();
#pragma unroll
        for (int cc = 0; cc < 4; cc++) {
            int ch = t + 256 * cc; int r = ch >> 3, c16 = ch & 7;
            bf16x8 va = *(const bf16x8*)(Ab + (long)(i0 + r) * 1024 + k0 + c16 * 8);
            *(bf16x8*)((char*)lA + r * 128 + LDS_SWZ(r, c16)) = va;
        }
#pragma unroll
        for (int cc = 0; cc < 2; cc++) {
            int ch = t + 256 * cc;
            if (ch < 384) {
                int r = ch >> 3, c16 = ch & 7;
                bf16x8 vb = *(const bf16x8*)(Bb + r * 1024 + k0 + c16 * 8);
                *(bf16x8*)((char*)lB + r * 128 + LDS_SWZ(r, c16)) = vb;
            }
        }
        __syncthreads();
#pragma unroll
        for (int kk = 0; kk < 2; kk++) {
            bf16x8 af[2], bfr[3];
#pragma unroll
            for (int m = 0; m < 2; m++) {
                int r = wm + m * 16 + lm;
                af[m] = *(const bf16x8*)((char*)lA + r * 128 + LDS_SWZ(r, kk * 4 + lg));
            }
#pragma unroll
            for (int n = 0; n < 3; n++) {
                int r = n * 16 + lm;
                bfr[n] = *(const bf16x8*)((char*)lB + r * 128 + LDS_SWZ(r, kk * 4 + lg));
            }
#pragma unroll
            for (int m = 0; m < 2; m++)
#pragma unroll
                for (int n = 0; n < 3; n++)
                    acc[m][n] = __builtin_amdgcn_mfma_f32_16x16x32_bf16(af[m], bfr[n], acc[m][n], 0, 0, 0);
        }
    }
#pragma unroll
    for (int m = 0; m < 2; m++)
#pragma unroll
        for (int n = 0; n < 3; n++) {
            const int col = h * 48 + n * 16 + lm;
#pragma unroll
            for (int r = 0; r < 4; r++) {
                const int row = i0 + wm + m * 16 + lg * 4 + r;
                float gv = g[row * 768 + col];
                go[row * 768 + col] = (bf16_t)(gv * acc[m][n][r]);
            }
        }
}

// ---------------------------------------------------------------------- launch
extern "C" void kernel_launch(void* const* d_in, const int* in_sizes, int n_in,
                              void* d_out, int out_size, void* d_ws, size_t ws_size,
                              hipStream_t stream)
{
    (void)in_sizes; (void)n_in;
    const float* a    = (const float*)d_in[0];
    const float* z    = (const float*)d_in[1];
    const float* mask = (const float*)d_in[2];
    const float* lnaw = (const float*)d_in[3];
    const float* lnab = (const float*)d_in[4];
    const float* lnzw = (const float*)d_in[5];
    const float* lnzb = (const float*)d_in[6];
    const float* Wq   = (const float*)d_in[7];
    const float* bq   = (const float*)d_in[8];
    const float* Wk   = (const float*)d_in[9];
    const float* Wv   = (const float*)d_in[10];
    const float* Wb   = (const float*)d_in[11];
    const float* Wg   = (const float*)d_in[12];
    const float* Wout = (const float*)d_in[13];

    char* p = (char*)d_ws; size_t off = 0;
    auto carve = [&](size_t bytes) -> void* {
        void* r = p + off; off += (bytes + 255) & ~(size_t)255; return r;
    };
    bf16_t* WT[5];
    for (int i = 0; i < 5; i++) WT[i] = (bf16_t*)carve(768 * 768 * 2);
    bf16_t* an  = (bf16_t*)carve(1024 * 768 * 2);
    bf16_t* qb  = (bf16_t*)carve(1024 * 768 * 2);
    bf16_t* kb  = (bf16_t*)carve(1024 * 768 * 2);
    bf16_t* vT  = (bf16_t*)carve(768 * 1024 * 2);
    float*  gf  = (float*) carve(1024 * 768 * 4);
    bf16_t* gob = (bf16_t*)carve(1024 * 768 * 2);
    bf16_t* WbWTp = (bf16_t*)carve(16 * 128 * 2);
    float* WbSp = (float*)carve(64);
    float* WbCp = (float*)carve(64);
    bf16_t* qkatt = (bf16_t*)carve((size_t)16 * 1024 * 1024 * 2);

    if (ws_size < off) {
        hipMemsetAsync(d_out, 0, (size_t)out_size * 4, stream);
        return;
    }

    WPack pk;
    pk.in[0] = Wq; pk.in[1] = Wk; pk.in[2] = Wv; pk.in[3] = Wg; pk.in[4] = Wout;
    for (int i = 0; i < 5; i++) pk.out[i] = WT[i];

    hipLaunchKernelGGL(k_prep_w, dim3(24, 24, 5), dim3(256), 0, stream, pk);
    hipLaunchKernelGGL(k_prep_wb, dim3(1), dim3(256), 0, stream, Wb, lnzw, lnzb, WbWTp, WbSp, WbCp);
    hipLaunchKernelGGL(k_ln_a, dim3(1024), dim3(256), 0, stream, a, lnaw, lnab, an);

    ProjPack pp;
    pp.A = an; pp.bias = bq;
    pp.BT[0] = WT[0]; pp.BT[1] = WT[1]; pp.BT[2] = WT[2]; pp.BT[3] = WT[3];
    pp.out[0] = (void*)qb; pp.out[1] = (void*)kb; pp.out[2] = (void*)vT; pp.out[3] = (void*)gf;
    hipLaunchKernelGGL(k_proj, dim3(8, 6, 4), dim3(256), 0, stream, pp);

    hipLaunchKernelGGL(k_qk, dim3(8, 8, 16), dim3(256), 0, stream, qb, kb, qkatt);
    hipLaunchKernelGGL(k_scores, dim3(1024), dim3(256), 0, stream, z, qkatt, WbWTp, WbSp, WbCp, mask);
    hipLaunchKernelGGL(k_pv, dim3(8, 16), dim3(256), 0, stream, qkatt, vT, gf, gob);
    hipLaunchKernelGGL(k_gemm768, dim3(8, 6), dim3(256), 0, stream, gob, WT[4], d_out, (const float*)nullptr, 4);
}